// Round 3
// baseline (184.741 us; speedup 1.0000x reference)
//
#include <hip/hip_runtime.h>

#define HW 4096
#define LCAP 1536      // per-block hit list (expected ~52/block)

typedef short bf16x8 __attribute__((ext_vector_type(8)));
typedef float f32x16 __attribute__((ext_vector_type(16)));

__device__ __forceinline__ ushort f2bf_rne(float f) {
    unsigned u = __float_as_uint(f);
    return (ushort)((u + 0x7FFFu + ((u >> 16) & 1u)) >> 16);
}

// ---------------------------------------------------------------------------
// W transpose: Wt[c][o] = W[o][c].
// ---------------------------------------------------------------------------
__global__ __launch_bounds__(256) void transpose_w_kernel(
    const float* __restrict__ Wm, float* __restrict__ Wt)
{
    const int o = blockIdx.x;        // 128
    const int c = threadIdx.x;       // 256
    Wt[c * 128 + o] = Wm[o * 256 + c];
}

// ---------------------------------------------------------------------------
// Kernel 1: 1x1-conv projection as an LDS-tiled vector GEMM (unchanged).
// Outputs: Qt/Pt fp32 [b][n][128], qnorm, bf16 packs in 32x32x16 fragment
// order: PK[b][t32][ks][lt][j] = proj[c=ks*16+(lt>>5)*8+j][n=t32*32+(lt&31)].
// ---------------------------------------------------------------------------
__global__ __launch_bounds__(256) void proj_kernel(
    const float* __restrict__ Fq, const float* __restrict__ Fp,
    const float* __restrict__ Wt, const float* __restrict__ bias,
    float* __restrict__ Qt, float* __restrict__ Pt,
    ushort* __restrict__ Qpk, ushort* __restrict__ Ppk,
    float* __restrict__ qnorm)
{
    __shared__ float Ws[64][128];    // 32 KB: c-chunk x o
    __shared__ float Xs[64][64];     // 16 KB: c-chunk x n
    __shared__ float psum[16][68];   // padded norm partials

    const int tid = threadIdx.x;
    const int z  = blockIdx.z;                 // 0: q, 1: p
    const float* __restrict__ X = z ? Fp : Fq;
    const int b  = blockIdx.y;
    const int n0 = blockIdx.x * 64;
    const int og = tid >> 4;                   // 0..15 -> o = og*8 .. +8
    const int ng = tid & 15;                   // 0..15 -> n = n0+ng*4 .. +4

    float acc[4][8];                           // [n][o]
    #pragma unroll
    for (int i = 0; i < 4; ++i)
        #pragma unroll
        for (int j = 0; j < 8; ++j) acc[i][j] = 0.f;

    for (int cc = 0; cc < 4; ++cc) {
        __syncthreads();                       // protect prior chunk's reads
        {
            const float4* src = (const float4*)(Wt + (size_t)cc * 64 * 128);
            float4* dst = (float4*)Ws;
            #pragma unroll
            for (int it = 0; it < 8; ++it) dst[it * 256 + tid] = src[it * 256 + tid];
        }
        #pragma unroll
        for (int it = 0; it < 4; ++it) {
            int f = it * 256 + tid;
            int r = f >> 4, n4 = f & 15;
            *(float4*)&Xs[r][n4 * 4] =
                *(const float4*)&X[(size_t)(b * 256 + cc * 64 + r) * HW + n0 + n4 * 4];
        }
        __syncthreads();

        for (int r = 0; r < 64; ++r) {
            float4 w0 = *(const float4*)&Ws[r][og * 8];
            float4 w1 = *(const float4*)&Ws[r][og * 8 + 4];
            float4 xv = *(const float4*)&Xs[r][ng * 4];
            float wa[8] = {w0.x, w0.y, w0.z, w0.w, w1.x, w1.y, w1.z, w1.w};
            float xa[4] = {xv.x, xv.y, xv.z, xv.w};
            #pragma unroll
            for (int i = 0; i < 4; ++i)
                #pragma unroll
                for (int j = 0; j < 8; ++j)
                    acc[i][j] += wa[j] * xa[i];
        }
    }

    {
        float4 b0 = *(const float4*)&bias[og * 8];
        float4 b1 = *(const float4*)&bias[og * 8 + 4];
        float ba[8] = {b0.x, b0.y, b0.z, b0.w, b1.x, b1.y, b1.z, b1.w};
        #pragma unroll
        for (int i = 0; i < 4; ++i)
            #pragma unroll
            for (int j = 0; j < 8; ++j) acc[i][j] += ba[j];
    }

    #pragma unroll
    for (int i = 0; i < 4; ++i) {
        float s = 0.f;
        #pragma unroll
        for (int j = 0; j < 8; ++j) s += acc[i][j] * acc[i][j];
        psum[og][ng * 4 + i] = s;
    }
    __syncthreads();
    float tot[4];
    #pragma unroll
    for (int i = 0; i < 4; ++i) {
        float s = 0.f;
        #pragma unroll
        for (int g = 0; g < 16; ++g) s += psum[g][ng * 4 + i];
        tot[i] = s;
    }

    if (z) {   // normalize p over its 128 channels
        #pragma unroll
        for (int i = 0; i < 4; ++i) {
            float s = 1.0f / sqrtf(tot[i]);
            #pragma unroll
            for (int j = 0; j < 8; ++j) acc[i][j] *= s;
        }
    } else if (og == 0) {
        #pragma unroll
        for (int i = 0; i < 4; ++i)
            qnorm[b * HW + n0 + ng * 4 + i] = sqrtf(tot[i]);
    }

    {
        float* __restrict__ T = z ? Pt : Qt;
        #pragma unroll
        for (int i = 0; i < 4; ++i) {
            size_t tb = ((size_t)b * HW + n0 + ng * 4 + i) * 128 + og * 8;
            *(float4*)&T[tb]     = make_float4(acc[i][0], acc[i][1], acc[i][2], acc[i][3]);
            *(float4*)&T[tb + 4] = make_float4(acc[i][4], acc[i][5], acc[i][6], acc[i][7]);
        }
    }
    {
        ushort* __restrict__ PK = z ? Ppk : Qpk;
        const int ks = og >> 1;
        #pragma unroll
        for (int i = 0; i < 4; ++i) {
            const int na  = n0 + ng * 4 + i;
            const int t32 = na >> 5;
            const int lt  = (na & 31) + 32 * (og & 1);
            ushort u[8];
            #pragma unroll
            for (int k = 0; k < 8; ++k) u[k] = f2bf_rne(acc[i][k]);
            size_t pk = ((((size_t)b * 128 + t32) * 8 + ks) * 64 + lt) * 8;
            uint4 w;
            w.x = (unsigned)u[0] | ((unsigned)u[1] << 16);
            w.y = (unsigned)u[2] | ((unsigned)u[3] << 16);
            w.z = (unsigned)u[4] | ((unsigned)u[5] << 16);
            w.w = (unsigned)u[6] | ((unsigned)u[7] << 16);
            *(uint4*)&PK[pk] = w;
        }
    }
}

// ---------------------------------------------------------------------------
// SINGLE sim pass, LDS-FREE: the packs are already in fragment order, so a
// fragment load from GLOBAL is fully coalesced (lane*16B).  Q fragments are
// hoisted to registers once; B fragments stream from L2 (Ppk slice is 1 MB,
// re-read by the 32 nb-blocks).  No __shared__, no barriers -> MFMA and VMEM
// overlap freely.  MFMA chain order identical to R2 -> bitwise-same codes.
// Outputs: Vmax (per n, per ms slice), SK u8 sketch, CM u8 group colmax
// (cm8 >= every code in the 16-byte word; round-up cushion).
// ---------------------------------------------------------------------------
__global__ __launch_bounds__(256, 2) void sim_sketch_kernel(
    const ushort* __restrict__ Qpk, const ushort* __restrict__ Ppk,
    const float* __restrict__ qnorm,
    float* __restrict__ Vmax, unsigned char* __restrict__ SK,
    unsigned char* __restrict__ CM)
{
    const int tid  = threadIdx.x;
    const int lane = tid & 63;
    const int w    = tid >> 6;
    const int nb   = blockIdx.x;
    const int b    = blockIdx.y;
    const int ms   = blockIdx.z;
    const int hi   = lane >> 5;

    // Q fragments: 8 x bf16x8 (32 VGPRs), loaded once, coalesced
    const ushort* __restrict__ qbase =
        Qpk + ((size_t)(b * 128 + nb * 4)) * 4096 + (size_t)lane * 8;
    bf16x8 qf[8];
    #pragma unroll
    for (int ks = 0; ks < 8; ++ks)
        qf[ks] = *(const bf16x8*)(qbase + (w * 8 + ks) * 512);

    // per-n reciprocal scales (same expression as scan side)
    float rq[16];
    #pragma unroll
    for (int r = 0; r < 16; ++r) {
        int nl_ = (r & 3) + 8 * (r >> 2) + 4 * hi;
        rq[r] = 256.0f / qnorm[b * HW + nb * 128 + w * 32 + nl_];
    }

    const size_t g16f = (size_t)b * 256 + (size_t)(nb * 4 + w) * 2 + hi;
    const int mb0 = ms * 1024 + (lane & 31);

    float bestv[16];
    #pragma unroll
    for (int r = 0; r < 16; ++r) bestv[r] = -1e30f;

    #pragma unroll 1
    for (int ch = 0; ch < 8; ++ch) {
        const ushort* __restrict__ pbase =
            Ppk + ((size_t)(b * 128 + ms * 32 + ch * 4)) * 4096 + (size_t)lane * 8;
        #pragma unroll 2
        for (int mtl = 0; mtl < 4; ++mtl) {
            f32x16 acc;
            #pragma unroll
            for (int r = 0; r < 16; ++r) acc[r] = 0.f;
            #pragma unroll
            for (int ks = 0; ks < 8; ++ks) {
                bf16x8 bb = *(const bf16x8*)(pbase + (mtl * 8 + ks) * 512);
                acc = __builtin_amdgcn_mfma_f32_32x32x16_bf16(qf[ks], bb, acc, 0, 0, 0);
            }
            #pragma unroll
            for (int r = 0; r < 16; ++r)
                bestv[r] = fmaxf(bestv[r], acc[r]);

            // scaled values; codes derive from exactly these products
            float x[16];
            #pragma unroll
            for (int r = 0; r < 16; ++r) x[r] = acc[r] * rq[r];

            // group colmax bound: cm8 >= rne(x[r]) for all r.
            // rne(x) <= x+0.5; trunc(y)+1 > y; fp slack < 1 code absorbed
            // by the integer-domain strict inequality.
            float c0 = fmaxf(fmaxf(fmaxf(x[0], x[1]), fmaxf(x[2], x[3])),
                             fmaxf(fmaxf(x[4], x[5]), fmaxf(x[6], x[7])));
            float c1 = fmaxf(fmaxf(fmaxf(x[8], x[9]), fmaxf(x[10], x[11])),
                             fmaxf(fmaxf(x[12], x[13]), fmaxf(x[14], x[15])));
            int cmi = (int)(fmaxf(c0, c1) + 0.5f) + 1;
            cmi = cmi < 0 ? 0 : (cmi > 255 ? 255 : cmi);

            unsigned dw[4] = {0u, 0u, 0u, 0u};
            #pragma unroll
            for (int r = 0; r < 16; ++r) {
#if __has_builtin(__builtin_amdgcn_cvt_pk_u8_f32)
                dw[r >> 2] = (unsigned)__builtin_amdgcn_cvt_pk_u8_f32(
                    x[r], (unsigned)(r & 3), (int)dw[r >> 2]);
#else
                int vi = (int)rintf(x[r]);
                vi = vi < 0 ? 0 : (vi > 255 ? 255 : vi);
                dw[r >> 2] |= (unsigned)vi << (8 * (r & 3));
#endif
            }
            const int m = mb0 + ch * 128 + mtl * 32;
            uint4 pk;
            pk.x = dw[0]; pk.y = dw[1]; pk.z = dw[2]; pk.w = dw[3];
            *(uint4*)(SK + ((g16f * 4096 + (size_t)m) << 4)) = pk;
            CM[g16f * 4096 + (size_t)m] = (unsigned char)cmi;
        }
    }

    #pragma unroll
    for (int r = 0; r < 16; ++r) {
        float v = bestv[r];
        #pragma unroll
        for (int d = 1; d < 32; d <<= 1)
            v = fmaxf(v, __shfl_xor(v, d, 64));
        if ((lane & 31) == 0) {
            int nl_ = (r & 3) + 8 * (r >> 2) + 4 * hi;
            int na = nb * 128 + w * 32 + nl_;
            Vmax[((size_t)b * HW + na) * 4 + ms] = v;
        }
    }
}

// ---------------------------------------------------------------------------
// fused init + threshold + scan + exact fp32 rescore.  One block per (b,g16):
// - inits the 16 best[n] slots it exclusively owns (no other block touches
//   them; overflow dots are handled inline in-block too)
// - computes t8 thresholds from Vmax/qnorm in-block (thresh kernel folded)
// - group-gates on the CM byte (skip 16B sketch word when cm8 < min t8)
// - byte-compares surviving words, exact fp32 dot per hit.
// ---------------------------------------------------------------------------
__device__ __noinline__ void dot_one_slow(
    const float* Qsrow, const float* __restrict__ Pt,
    int b, int m, int n, unsigned long long* __restrict__ best)
{
    const float4* __restrict__ pr = (const float4*)&Pt[((size_t)b * HW + m) * 128];
    float acc = 0.f;
    #pragma unroll
    for (int k = 0; k < 32; ++k) {
        float4 pv = pr[k];
        float4 qv = *(const float4*)&Qsrow[k * 4];
        acc += qv.x * pv.x + qv.y * pv.y + qv.z * pv.z + qv.w * pv.w;
    }
    unsigned u = __float_as_uint(acc);
    unsigned kk = (u & 0x80000000u) ? ~u : (u | 0x80000000u);
    unsigned long long key = ((unsigned long long)kk << 32) | (unsigned)(4095 - m);
    atomicMax(&best[(size_t)b * HW + n], key);
}

__global__ __launch_bounds__(256) void scan_rescore_kernel(
    const unsigned char* __restrict__ SK, const unsigned char* __restrict__ CM,
    const float* __restrict__ Vmax, const float* __restrict__ qnorm,
    const float* __restrict__ Qt, const float* __restrict__ Pt,
    unsigned long long* __restrict__ best)
{
    __shared__ float Qs[16][132];
    __shared__ int nlist[16];
    __shared__ int t8s[16];
    __shared__ ushort hl[LCAP];
    __shared__ unsigned lcnt;

    const int fg  = blockIdx.x;               // b*256 + g16
    const int tid = threadIdx.x;
    const int b = fg >> 8, g = fg & 255, t = g >> 1, gs = g & 1;

    if (tid == 0) lcnt = 0u;
    if (tid < 16) {
        int n = t * 32 + (tid & 3) + 8 * (tid >> 2) + 4 * gs;
        nlist[tid] = n;
        best[(size_t)b * HW + n] = 0ull;      // folded init: block-exclusive n
        float gmax = -1e30f;
        #pragma unroll
        for (int s = 0; s < 4; ++s)
            gmax = fmaxf(gmax, Vmax[((size_t)b * HW + n) * 4 + s]);
        float qn  = qnorm[b * HW + n];
        float thr = gmax - (0.016f * qn + 1e-6f);
        int tt = (int)floorf(thr * (256.0f / qn)) - 1;
        t8s[tid] = tt < 0 ? 0 : (tt > 255 ? 255 : tt);
    }
    __syncthreads();

    #pragma unroll
    for (int it = 0; it < 2; ++it) {
        int idx = it * 256 + tid;
        int row = idx >> 5, c4 = (idx & 31) * 4;
        *(float4*)&Qs[row][c4] =
            *(const float4*)&Qt[((size_t)b * HW + nlist[row]) * 128 + c4];
    }

    int myt[16];
    #pragma unroll
    for (int j = 0; j < 16; ++j) myt[j] = t8s[j];
    int gmin = myt[0];
    #pragma unroll
    for (int j = 1; j < 16; ++j) gmin = min(gmin, myt[j]);
    __syncthreads();   // Qs staged (inline-overflow dots read it)

    const unsigned char* __restrict__ cmrow = CM + ((size_t)fg << 12);
    const unsigned char* __restrict__ skrow = SK + ((size_t)fg << 16);

    #pragma unroll
    for (int it = 0; it < 4; ++it) {
        int m0 = (it * 256 + tid) * 4;
        unsigned cm4 = *(const unsigned*)(cmrow + m0);
        #pragma unroll
        for (int k = 0; k < 4; ++k) {
            int cmv = (int)((cm4 >> (8 * k)) & 255u);
            if (cmv >= gmin) {
                int m = m0 + k;
                uint4 v = *(const uint4*)(skrow + ((size_t)m << 4));
                unsigned wv[4] = {v.x, v.y, v.z, v.w};
                #pragma unroll
                for (int d = 0; d < 4; ++d) {
                    #pragma unroll
                    for (int kk = 0; kk < 4; ++kk) {
                        int bv = (int)((wv[d] >> (8 * kk)) & 255u);
                        int j = d * 4 + kk;
                        if (bv >= myt[j]) {
                            unsigned pos = atomicAdd(&lcnt, 1u);
                            if (pos < LCAP) {
                                hl[pos] = (ushort)((j << 12) | m);
                            } else {   // overflow: inline (rare/never)
                                dot_one_slow(&Qs[j][0], Pt, b, m, nlist[j], best);
                            }
                        }
                    }
                }
            }
        }
    }

    __syncthreads();
    unsigned cnt = lcnt < LCAP ? lcnt : LCAP;
    for (unsigned p = tid; p < cnt; p += 256) {
        int e = hl[p];
        int j = e >> 12, m = e & 4095;
        const float4* __restrict__ pr = (const float4*)&Pt[((size_t)b * HW + m) * 128];
        float acc = 0.f;
        #pragma unroll
        for (int k = 0; k < 32; ++k) {
            float4 pv = pr[k];
            float4 qv = *(const float4*)&Qs[j][k * 4];
            acc += qv.x * pv.x + qv.y * pv.y + qv.z * pv.z + qv.w * pv.w;
        }
        unsigned u = __float_as_uint(acc);
        unsigned kk = (u & 0x80000000u) ? ~u : (u | 0x80000000u);
        unsigned long long key = ((unsigned long long)kk << 32) | (unsigned)(4095 - m);
        atomicMax(&best[(size_t)b * HW + nlist[j]], key);
    }
}

// ---------------------------------------------------------------------------
// gather: out[b][c][n] = Fp[b][c][m(n)]; stage each 16 KB Fp row in LDS.
// ---------------------------------------------------------------------------
__global__ __launch_bounds__(256) void gather_kernel(
    const float* __restrict__ Fp, const unsigned long long* __restrict__ best,
    float* __restrict__ out)
{
    __shared__ float row[4096];
    const int blk = blockIdx.x;      // 1024 = 4b x 256c
    const int c = blk & 255;
    const int b = blk >> 8;
    const int tid = threadIdx.x;

    const float* __restrict__ src = Fp + ((size_t)b * 256 + c) * HW;
    #pragma unroll
    for (int it = 0; it < 4; ++it) {
        int f = it * 256 + tid;
        *(float4*)&row[f * 4] = *(const float4*)&src[f * 4];
    }
    __syncthreads();

    float* __restrict__ dst = out + ((size_t)b * 256 + c) * HW;
    #pragma unroll
    for (int it = 0; it < 16; ++it) {
        int n = it * 256 + tid;
        int m = 4095 - (int)(best[(size_t)b * HW + n] & 0xFFFull);
        dst[n] = row[m];
    }
}

extern "C" void kernel_launch(void* const* d_in, const int* in_sizes, int n_in,
                              void* d_out, int out_size, void* d_ws, size_t ws_size,
                              hipStream_t stream) {
    const float* Fq   = (const float*)d_in[0];
    const float* Fp   = (const float*)d_in[1];
    const float* Wm   = (const float*)d_in[2];
    const float* bias = (const float*)d_in[3];
    float* out = (float*)d_out;

    char* base = (char*)d_ws;
    float*  Qt    = (float*)(base);                               // 8 MB
    float*  Pt    = (float*)(base + (8u << 20));                  // 8 MB
    ushort* Qpk   = (ushort*)(base + (16u << 20));                // 4 MB
    ushort* Ppk   = (ushort*)(base + (20u << 20));                // 4 MB
    unsigned char* SK = (unsigned char*)(base + (24u << 20));     // 64 MB
    unsigned char* CM = (unsigned char*)(base + (88u << 20));     // 4 MB
    char* x = base + (92u << 20);
    float*  qnorm = (float*)x;              x += 65536;           // 64 KB
    float*  Vmax  = (float*)x;              x += 262144;          // 256 KB
    unsigned long long* best = (unsigned long long*)x; x += 131072; // 128 KB
    float*  Wtg   = (float*)x;                                    // 128 KB

    transpose_w_kernel<<<128, 256, 0, stream>>>(Wm, Wtg);
    proj_kernel<<<dim3(64, 4, 2), 256, 0, stream>>>(Fq, Fp, Wtg, bias,
                                                    Qt, Pt, Qpk, Ppk, qnorm);
    sim_sketch_kernel<<<dim3(32, 4, 4), 256, 0, stream>>>(Qpk, Ppk, qnorm,
                                                          Vmax, SK, CM);
    scan_rescore_kernel<<<1024, 256, 0, stream>>>(SK, CM, Vmax, qnorm,
                                                  Qt, Pt, best);
    gather_kernel<<<1024, 256, 0, stream>>>(Fp, best, out);
}

// Round 4
// 184.190 us; speedup vs baseline: 1.0030x; 1.0030x over previous
//
#include <hip/hip_runtime.h>

#define HW 4096
#define LCAP 1536      // per-block hit list (expected ~52/block)

typedef short bf16x8 __attribute__((ext_vector_type(8)));
typedef float f32x16 __attribute__((ext_vector_type(16)));

__device__ __forceinline__ ushort f2bf_rne(float f) {
    unsigned u = __float_as_uint(f);
    return (ushort)((u + 0x7FFFu + ((u >> 16) & 1u)) >> 16);
}

// ---------------------------------------------------------------------------
// W transpose: Wt[c][o] = W[o][c].
// ---------------------------------------------------------------------------
__global__ __launch_bounds__(256) void transpose_w_kernel(
    const float* __restrict__ Wm, float* __restrict__ Wt)
{
    const int o = blockIdx.x;        // 128
    const int c = threadIdx.x;       // 256
    Wt[c * 128 + o] = Wm[o * 256 + c];
}

// ---------------------------------------------------------------------------
// Kernel 1: 1x1-conv projection as an LDS-tiled vector GEMM (unchanged).
// Outputs: Qt/Pt fp32 [b][n][128], qnorm, bf16 packs in 32x32x16 fragment
// order: PK[b][t32][ks][lt][j] = proj[c=ks*16+(lt>>5)*8+j][n=t32*32+(lt&31)].
// ---------------------------------------------------------------------------
__global__ __launch_bounds__(256) void proj_kernel(
    const float* __restrict__ Fq, const float* __restrict__ Fp,
    const float* __restrict__ Wt, const float* __restrict__ bias,
    float* __restrict__ Qt, float* __restrict__ Pt,
    ushort* __restrict__ Qpk, ushort* __restrict__ Ppk,
    float* __restrict__ qnorm)
{
    __shared__ float Ws[64][128];    // 32 KB: c-chunk x o
    __shared__ float Xs[64][64];     // 16 KB: c-chunk x n
    __shared__ float psum[16][68];   // padded norm partials

    const int tid = threadIdx.x;
    const int z  = blockIdx.z;                 // 0: q, 1: p
    const float* __restrict__ X = z ? Fp : Fq;
    const int b  = blockIdx.y;
    const int n0 = blockIdx.x * 64;
    const int og = tid >> 4;                   // 0..15 -> o = og*8 .. +8
    const int ng = tid & 15;                   // 0..15 -> n = n0+ng*4 .. +4

    float acc[4][8];                           // [n][o]
    #pragma unroll
    for (int i = 0; i < 4; ++i)
        #pragma unroll
        for (int j = 0; j < 8; ++j) acc[i][j] = 0.f;

    for (int cc = 0; cc < 4; ++cc) {
        __syncthreads();                       // protect prior chunk's reads
        {
            const float4* src = (const float4*)(Wt + (size_t)cc * 64 * 128);
            float4* dst = (float4*)Ws;
            #pragma unroll
            for (int it = 0; it < 8; ++it) dst[it * 256 + tid] = src[it * 256 + tid];
        }
        #pragma unroll
        for (int it = 0; it < 4; ++it) {
            int f = it * 256 + tid;
            int r = f >> 4, n4 = f & 15;
            *(float4*)&Xs[r][n4 * 4] =
                *(const float4*)&X[(size_t)(b * 256 + cc * 64 + r) * HW + n0 + n4 * 4];
        }
        __syncthreads();

        for (int r = 0; r < 64; ++r) {
            float4 w0 = *(const float4*)&Ws[r][og * 8];
            float4 w1 = *(const float4*)&Ws[r][og * 8 + 4];
            float4 xv = *(const float4*)&Xs[r][ng * 4];
            float wa[8] = {w0.x, w0.y, w0.z, w0.w, w1.x, w1.y, w1.z, w1.w};
            float xa[4] = {xv.x, xv.y, xv.z, xv.w};
            #pragma unroll
            for (int i = 0; i < 4; ++i)
                #pragma unroll
                for (int j = 0; j < 8; ++j)
                    acc[i][j] += wa[j] * xa[i];
        }
    }

    {
        float4 b0 = *(const float4*)&bias[og * 8];
        float4 b1 = *(const float4*)&bias[og * 8 + 4];
        float ba[8] = {b0.x, b0.y, b0.z, b0.w, b1.x, b1.y, b1.z, b1.w};
        #pragma unroll
        for (int i = 0; i < 4; ++i)
            #pragma unroll
            for (int j = 0; j < 8; ++j) acc[i][j] += ba[j];
    }

    #pragma unroll
    for (int i = 0; i < 4; ++i) {
        float s = 0.f;
        #pragma unroll
        for (int j = 0; j < 8; ++j) s += acc[i][j] * acc[i][j];
        psum[og][ng * 4 + i] = s;
    }
    __syncthreads();
    float tot[4];
    #pragma unroll
    for (int i = 0; i < 4; ++i) {
        float s = 0.f;
        #pragma unroll
        for (int g = 0; g < 16; ++g) s += psum[g][ng * 4 + i];
        tot[i] = s;
    }

    if (z) {   // normalize p over its 128 channels
        #pragma unroll
        for (int i = 0; i < 4; ++i) {
            float s = 1.0f / sqrtf(tot[i]);
            #pragma unroll
            for (int j = 0; j < 8; ++j) acc[i][j] *= s;
        }
    } else if (og == 0) {
        #pragma unroll
        for (int i = 0; i < 4; ++i)
            qnorm[b * HW + n0 + ng * 4 + i] = sqrtf(tot[i]);
    }

    {
        float* __restrict__ T = z ? Pt : Qt;
        #pragma unroll
        for (int i = 0; i < 4; ++i) {
            size_t tb = ((size_t)b * HW + n0 + ng * 4 + i) * 128 + og * 8;
            *(float4*)&T[tb]     = make_float4(acc[i][0], acc[i][1], acc[i][2], acc[i][3]);
            *(float4*)&T[tb + 4] = make_float4(acc[i][4], acc[i][5], acc[i][6], acc[i][7]);
        }
    }
    {
        ushort* __restrict__ PK = z ? Ppk : Qpk;
        const int ks = og >> 1;
        #pragma unroll
        for (int i = 0; i < 4; ++i) {
            const int na  = n0 + ng * 4 + i;
            const int t32 = na >> 5;
            const int lt  = (na & 31) + 32 * (og & 1);
            ushort u[8];
            #pragma unroll
            for (int k = 0; k < 8; ++k) u[k] = f2bf_rne(acc[i][k]);
            size_t pk = ((((size_t)b * 128 + t32) * 8 + ks) * 64 + lt) * 8;
            uint4 w;
            w.x = (unsigned)u[0] | ((unsigned)u[1] << 16);
            w.y = (unsigned)u[2] | ((unsigned)u[3] << 16);
            w.z = (unsigned)u[4] | ((unsigned)u[5] << 16);
            w.w = (unsigned)u[6] | ((unsigned)u[7] << 16);
            *(uint4*)&PK[pk] = w;
        }
    }
}

// ---------------------------------------------------------------------------
// SINGLE sim pass, LDS-free, grid-split for occupancy.  R3 forensics: grid
// (32,4,4)=512 blocks capped residency at ~8 waves/CU (Occupancy 19.6%,
// MfmaUtil 11.7%) -> latency-bound on the L2 fragment loads feeding the
// dependent MFMA chain.  Now (32,4,16)=2048 blocks (~28 waves/CU at 68
// VGPR): each block does 256 m's.  Per-(n,m) MFMA chain order unchanged ->
// bitwise-same codes/Vmax (16 partial slices merged by the same fmaxf).
// ---------------------------------------------------------------------------
__global__ __launch_bounds__(256, 4) void sim_sketch_kernel(
    const ushort* __restrict__ Qpk, const ushort* __restrict__ Ppk,
    const float* __restrict__ qnorm,
    float* __restrict__ Vmax, unsigned char* __restrict__ SK,
    unsigned char* __restrict__ CM)
{
    const int tid  = threadIdx.x;
    const int lane = tid & 63;
    const int w    = tid >> 6;
    const int nb   = blockIdx.x;
    const int b    = blockIdx.y;
    const int ms   = blockIdx.z;               // 0..15, 256 m's each
    const int hi   = lane >> 5;

    // Q fragments: 8 x bf16x8 (32 VGPRs), loaded once, coalesced
    const ushort* __restrict__ qbase =
        Qpk + ((size_t)(b * 128 + nb * 4)) * 4096 + (size_t)lane * 8;
    bf16x8 qf[8];
    #pragma unroll
    for (int ks = 0; ks < 8; ++ks)
        qf[ks] = *(const bf16x8*)(qbase + (w * 8 + ks) * 512);

    // per-n reciprocal scales (same expression as scan side)
    float rq[16];
    #pragma unroll
    for (int r = 0; r < 16; ++r) {
        int nl_ = (r & 3) + 8 * (r >> 2) + 4 * hi;
        rq[r] = 256.0f / qnorm[b * HW + nb * 128 + w * 32 + nl_];
    }

    const size_t g16f = (size_t)b * 256 + (size_t)(nb * 4 + w) * 2 + hi;
    const int mb0 = ms * 256 + (lane & 31);

    float bestv[16];
    #pragma unroll
    for (int r = 0; r < 16; ++r) bestv[r] = -1e30f;

    #pragma unroll 1
    for (int ch = 0; ch < 2; ++ch) {
        const ushort* __restrict__ pbase =
            Ppk + ((size_t)(b * 128 + ms * 8 + ch * 4)) * 4096 + (size_t)lane * 8;
        #pragma unroll 2
        for (int mtl = 0; mtl < 4; ++mtl) {
            f32x16 acc;
            #pragma unroll
            for (int r = 0; r < 16; ++r) acc[r] = 0.f;
            #pragma unroll
            for (int ks = 0; ks < 8; ++ks) {
                bf16x8 bb = *(const bf16x8*)(pbase + (mtl * 8 + ks) * 512);
                acc = __builtin_amdgcn_mfma_f32_32x32x16_bf16(qf[ks], bb, acc, 0, 0, 0);
            }
            #pragma unroll
            for (int r = 0; r < 16; ++r)
                bestv[r] = fmaxf(bestv[r], acc[r]);

            // scaled values; codes derive from exactly these products
            float x[16];
            #pragma unroll
            for (int r = 0; r < 16; ++r) x[r] = acc[r] * rq[r];

            // group colmax bound: cm8 >= rne(x[r]) for all r.
            float c0 = fmaxf(fmaxf(fmaxf(x[0], x[1]), fmaxf(x[2], x[3])),
                             fmaxf(fmaxf(x[4], x[5]), fmaxf(x[6], x[7])));
            float c1 = fmaxf(fmaxf(fmaxf(x[8], x[9]), fmaxf(x[10], x[11])),
                             fmaxf(fmaxf(x[12], x[13]), fmaxf(x[14], x[15])));
            int cmi = (int)(fmaxf(c0, c1) + 0.5f) + 1;
            cmi = cmi < 0 ? 0 : (cmi > 255 ? 255 : cmi);

            unsigned dw[4] = {0u, 0u, 0u, 0u};
            #pragma unroll
            for (int r = 0; r < 16; ++r) {
#if __has_builtin(__builtin_amdgcn_cvt_pk_u8_f32)
                dw[r >> 2] = (unsigned)__builtin_amdgcn_cvt_pk_u8_f32(
                    x[r], (unsigned)(r & 3), (int)dw[r >> 2]);
#else
                int vi = (int)rintf(x[r]);
                vi = vi < 0 ? 0 : (vi > 255 ? 255 : vi);
                dw[r >> 2] |= (unsigned)vi << (8 * (r & 3));
#endif
            }
            const int m = mb0 + ch * 128 + mtl * 32;
            uint4 pk;
            pk.x = dw[0]; pk.y = dw[1]; pk.z = dw[2]; pk.w = dw[3];
            *(uint4*)(SK + ((g16f * 4096 + (size_t)m) << 4)) = pk;
            CM[g16f * 4096 + (size_t)m] = (unsigned char)cmi;
        }
    }

    #pragma unroll
    for (int r = 0; r < 16; ++r) {
        float v = bestv[r];
        #pragma unroll
        for (int d = 1; d < 32; d <<= 1)
            v = fmaxf(v, __shfl_xor(v, d, 64));
        if ((lane & 31) == 0) {
            int nl_ = (r & 3) + 8 * (r >> 2) + 4 * hi;
            int na = nb * 128 + w * 32 + nl_;
            Vmax[((size_t)b * HW + na) * 16 + ms] = v;
        }
    }
}

// ---------------------------------------------------------------------------
// fused init + threshold + scan + exact fp32 rescore.  One block per (b,g16):
// - inits the 16 best[n] slots it exclusively owns
// - computes t8 thresholds from Vmax (16 slices)/qnorm in-block
// - group-gates on the CM byte (skip 16B sketch word when cm8 < min t8)
// - byte-compares surviving words, exact fp32 dot per hit.
// ---------------------------------------------------------------------------
__device__ __noinline__ void dot_one_slow(
    const float* Qsrow, const float* __restrict__ Pt,
    int b, int m, int n, unsigned long long* __restrict__ best)
{
    const float4* __restrict__ pr = (const float4*)&Pt[((size_t)b * HW + m) * 128];
    float acc = 0.f;
    #pragma unroll
    for (int k = 0; k < 32; ++k) {
        float4 pv = pr[k];
        float4 qv = *(const float4*)&Qsrow[k * 4];
        acc += qv.x * pv.x + qv.y * pv.y + qv.z * pv.z + qv.w * pv.w;
    }
    unsigned u = __float_as_uint(acc);
    unsigned kk = (u & 0x80000000u) ? ~u : (u | 0x80000000u);
    unsigned long long key = ((unsigned long long)kk << 32) | (unsigned)(4095 - m);
    atomicMax(&best[(size_t)b * HW + n], key);
}

__global__ __launch_bounds__(256) void scan_rescore_kernel(
    const unsigned char* __restrict__ SK, const unsigned char* __restrict__ CM,
    const float* __restrict__ Vmax, const float* __restrict__ qnorm,
    const float* __restrict__ Qt, const float* __restrict__ Pt,
    unsigned long long* __restrict__ best)
{
    __shared__ float Qs[16][132];
    __shared__ int nlist[16];
    __shared__ int t8s[16];
    __shared__ ushort hl[LCAP];
    __shared__ unsigned lcnt;

    const int fg  = blockIdx.x;               // b*256 + g16
    const int tid = threadIdx.x;
    const int b = fg >> 8, g = fg & 255, t = g >> 1, gs = g & 1;

    if (tid == 0) lcnt = 0u;
    if (tid < 16) {
        int n = t * 32 + (tid & 3) + 8 * (tid >> 2) + 4 * gs;
        nlist[tid] = n;
        best[(size_t)b * HW + n] = 0ull;      // folded init: block-exclusive n
        float gmax = -1e30f;
        #pragma unroll
        for (int s = 0; s < 16; ++s)
            gmax = fmaxf(gmax, Vmax[((size_t)b * HW + n) * 16 + s]);
        float qn  = qnorm[b * HW + n];
        float thr = gmax - (0.016f * qn + 1e-6f);
        int tt = (int)floorf(thr * (256.0f / qn)) - 1;
        t8s[tid] = tt < 0 ? 0 : (tt > 255 ? 255 : tt);
    }
    __syncthreads();

    #pragma unroll
    for (int it = 0; it < 2; ++it) {
        int idx = it * 256 + tid;
        int row = idx >> 5, c4 = (idx & 31) * 4;
        *(float4*)&Qs[row][c4] =
            *(const float4*)&Qt[((size_t)b * HW + nlist[row]) * 128 + c4];
    }

    int myt[16];
    #pragma unroll
    for (int j = 0; j < 16; ++j) myt[j] = t8s[j];
    int gmin = myt[0];
    #pragma unroll
    for (int j = 1; j < 16; ++j) gmin = min(gmin, myt[j]);
    __syncthreads();   // Qs staged (inline-overflow dots read it)

    const unsigned char* __restrict__ cmrow = CM + ((size_t)fg << 12);
    const unsigned char* __restrict__ skrow = SK + ((size_t)fg << 16);

    #pragma unroll
    for (int it = 0; it < 4; ++it) {
        int m0 = (it * 256 + tid) * 4;
        unsigned cm4 = *(const unsigned*)(cmrow + m0);
        #pragma unroll
        for (int k = 0; k < 4; ++k) {
            int cmv = (int)((cm4 >> (8 * k)) & 255u);
            if (cmv >= gmin) {
                int m = m0 + k;
                uint4 v = *(const uint4*)(skrow + ((size_t)m << 4));
                unsigned wv[4] = {v.x, v.y, v.z, v.w};
                #pragma unroll
                for (int d = 0; d < 4; ++d) {
                    #pragma unroll
                    for (int kk = 0; kk < 4; ++kk) {
                        int bv = (int)((wv[d] >> (8 * kk)) & 255u);
                        int j = d * 4 + kk;
                        if (bv >= myt[j]) {
                            unsigned pos = atomicAdd(&lcnt, 1u);
                            if (pos < LCAP) {
                                hl[pos] = (ushort)((j << 12) | m);
                            } else {   // overflow: inline (rare/never)
                                dot_one_slow(&Qs[j][0], Pt, b, m, nlist[j], best);
                            }
                        }
                    }
                }
            }
        }
    }

    __syncthreads();
    unsigned cnt = lcnt < LCAP ? lcnt : LCAP;
    for (unsigned p = tid; p < cnt; p += 256) {
        int e = hl[p];
        int j = e >> 12, m = e & 4095;
        const float4* __restrict__ pr = (const float4*)&Pt[((size_t)b * HW + m) * 128];
        float acc = 0.f;
        #pragma unroll
        for (int k = 0; k < 32; ++k) {
            float4 pv = pr[k];
            float4 qv = *(const float4*)&Qs[j][k * 4];
            acc += qv.x * pv.x + qv.y * pv.y + qv.z * pv.z + qv.w * pv.w;
        }
        unsigned u = __float_as_uint(acc);
        unsigned kk = (u & 0x80000000u) ? ~u : (u | 0x80000000u);
        unsigned long long key = ((unsigned long long)kk << 32) | (unsigned)(4095 - m);
        atomicMax(&best[(size_t)b * HW + nlist[j]], key);
    }
}

// ---------------------------------------------------------------------------
// gather: out[b][c][n] = Fp[b][c][m(n)]; stage each 16 KB Fp row in LDS.
// ---------------------------------------------------------------------------
__global__ __launch_bounds__(256) void gather_kernel(
    const float* __restrict__ Fp, const unsigned long long* __restrict__ best,
    float* __restrict__ out)
{
    __shared__ float row[4096];
    const int blk = blockIdx.x;      // 1024 = 4b x 256c
    const int c = blk & 255;
    const int b = blk >> 8;
    const int tid = threadIdx.x;

    const float* __restrict__ src = Fp + ((size_t)b * 256 + c) * HW;
    #pragma unroll
    for (int it = 0; it < 4; ++it) {
        int f = it * 256 + tid;
        *(float4*)&row[f * 4] = *(const float4*)&src[f * 4];
    }
    __syncthreads();

    float* __restrict__ dst = out + ((size_t)b * 256 + c) * HW;
    #pragma unroll
    for (int it = 0; it < 16; ++it) {
        int n = it * 256 + tid;
        int m = 4095 - (int)(best[(size_t)b * HW + n] & 0xFFFull);
        dst[n] = row[m];
    }
}

extern "C" void kernel_launch(void* const* d_in, const int* in_sizes, int n_in,
                              void* d_out, int out_size, void* d_ws, size_t ws_size,
                              hipStream_t stream) {
    const float* Fq   = (const float*)d_in[0];
    const float* Fp   = (const float*)d_in[1];
    const float* Wm   = (const float*)d_in[2];
    const float* bias = (const float*)d_in[3];
    float* out = (float*)d_out;

    char* base = (char*)d_ws;
    float*  Qt    = (float*)(base);                               // 8 MB
    float*  Pt    = (float*)(base + (8u << 20));                  // 8 MB
    ushort* Qpk   = (ushort*)(base + (16u << 20));                // 4 MB
    ushort* Ppk   = (ushort*)(base + (20u << 20));                // 4 MB
    unsigned char* SK = (unsigned char*)(base + (24u << 20));     // 64 MB
    unsigned char* CM = (unsigned char*)(base + (88u << 20));     // 4 MB
    char* x = base + (92u << 20);
    float*  qnorm = (float*)x;              x += 65536;           // 64 KB
    float*  Vmax  = (float*)x;              x += 1048576;         // 1 MB (16 slices)
    unsigned long long* best = (unsigned long long*)x; x += 131072; // 128 KB
    float*  Wtg   = (float*)x;                                    // 128 KB

    transpose_w_kernel<<<128, 256, 0, stream>>>(Wm, Wtg);
    proj_kernel<<<dim3(64, 4, 2), 256, 0, stream>>>(Fq, Fp, Wtg, bias,
                                                    Qt, Pt, Qpk, Ppk, qnorm);
    sim_sketch_kernel<<<dim3(32, 4, 16), 256, 0, stream>>>(Qpk, Ppk, qnorm,
                                                           Vmax, SK, CM);
    scan_rescore_kernel<<<1024, 256, 0, stream>>>(SK, CM, Vmax, qnorm,
                                                  Qt, Pt, best);
    gather_kernel<<<1024, 256, 0, stream>>>(Fp, best, out);
}

// Round 5
// 179.591 us; speedup vs baseline: 1.0287x; 1.0256x over previous
//
#include <hip/hip_runtime.h>

#define HW 4096
#define LCAP 1536      // per-block hit list (expected ~52/block)

typedef short bf16x8 __attribute__((ext_vector_type(8)));
typedef float f32x16 __attribute__((ext_vector_type(16)));

__device__ __forceinline__ ushort f2bf_rne(float f) {
    unsigned u = __float_as_uint(f);
    return (ushort)((u + 0x7FFFu + ((u >> 16) & 1u)) >> 16);
}

// ---------------------------------------------------------------------------
// W transpose: Wt[c][o] = W[o][c].
// ---------------------------------------------------------------------------
__global__ __launch_bounds__(256) void transpose_w_kernel(
    const float* __restrict__ Wm, float* __restrict__ Wt)
{
    const int o = blockIdx.x;        // 128
    const int c = threadIdx.x;       // 256
    Wt[c * 128 + o] = Wm[o * 256 + c];
}

// ---------------------------------------------------------------------------
// Kernel 1: 1x1-conv projection as an LDS-tiled vector GEMM (unchanged).
// Outputs: Qt/Pt fp32 [b][n][128], qnorm, bf16 packs in 32x32x16 fragment
// order: PK[b][t32][ks][lt][j] = proj[c=ks*16+(lt>>5)*8+j][n=t32*32+(lt&31)].
// ---------------------------------------------------------------------------
__global__ __launch_bounds__(256) void proj_kernel(
    const float* __restrict__ Fq, const float* __restrict__ Fp,
    const float* __restrict__ Wt, const float* __restrict__ bias,
    float* __restrict__ Qt, float* __restrict__ Pt,
    ushort* __restrict__ Qpk, ushort* __restrict__ Ppk,
    float* __restrict__ qnorm)
{
    __shared__ float Ws[64][128];    // 32 KB: c-chunk x o
    __shared__ float Xs[64][64];     // 16 KB: c-chunk x n
    __shared__ float psum[16][68];   // padded norm partials

    const int tid = threadIdx.x;
    const int z  = blockIdx.z;                 // 0: q, 1: p
    const float* __restrict__ X = z ? Fp : Fq;
    const int b  = blockIdx.y;
    const int n0 = blockIdx.x * 64;
    const int og = tid >> 4;                   // 0..15 -> o = og*8 .. +8
    const int ng = tid & 15;                   // 0..15 -> n = n0+ng*4 .. +4

    float acc[4][8];                           // [n][o]
    #pragma unroll
    for (int i = 0; i < 4; ++i)
        #pragma unroll
        for (int j = 0; j < 8; ++j) acc[i][j] = 0.f;

    for (int cc = 0; cc < 4; ++cc) {
        __syncthreads();                       // protect prior chunk's reads
        {
            const float4* src = (const float4*)(Wt + (size_t)cc * 64 * 128);
            float4* dst = (float4*)Ws;
            #pragma unroll
            for (int it = 0; it < 8; ++it) dst[it * 256 + tid] = src[it * 256 + tid];
        }
        #pragma unroll
        for (int it = 0; it < 4; ++it) {
            int f = it * 256 + tid;
            int r = f >> 4, n4 = f & 15;
            *(float4*)&Xs[r][n4 * 4] =
                *(const float4*)&X[(size_t)(b * 256 + cc * 64 + r) * HW + n0 + n4 * 4];
        }
        __syncthreads();

        for (int r = 0; r < 64; ++r) {
            float4 w0 = *(const float4*)&Ws[r][og * 8];
            float4 w1 = *(const float4*)&Ws[r][og * 8 + 4];
            float4 xv = *(const float4*)&Xs[r][ng * 4];
            float wa[8] = {w0.x, w0.y, w0.z, w0.w, w1.x, w1.y, w1.z, w1.w};
            float xa[4] = {xv.x, xv.y, xv.z, xv.w};
            #pragma unroll
            for (int i = 0; i < 4; ++i)
                #pragma unroll
                for (int j = 0; j < 8; ++j)
                    acc[i][j] += wa[j] * xa[i];
        }
    }

    {
        float4 b0 = *(const float4*)&bias[og * 8];
        float4 b1 = *(const float4*)&bias[og * 8 + 4];
        float ba[8] = {b0.x, b0.y, b0.z, b0.w, b1.x, b1.y, b1.z, b1.w};
        #pragma unroll
        for (int i = 0; i < 4; ++i)
            #pragma unroll
            for (int j = 0; j < 8; ++j) acc[i][j] += ba[j];
    }

    #pragma unroll
    for (int i = 0; i < 4; ++i) {
        float s = 0.f;
        #pragma unroll
        for (int j = 0; j < 8; ++j) s += acc[i][j] * acc[i][j];
        psum[og][ng * 4 + i] = s;
    }
    __syncthreads();
    float tot[4];
    #pragma unroll
    for (int i = 0; i < 4; ++i) {
        float s = 0.f;
        #pragma unroll
        for (int g = 0; g < 16; ++g) s += psum[g][ng * 4 + i];
        tot[i] = s;
    }

    if (z) {   // normalize p over its 128 channels
        #pragma unroll
        for (int i = 0; i < 4; ++i) {
            float s = 1.0f / sqrtf(tot[i]);
            #pragma unroll
            for (int j = 0; j < 8; ++j) acc[i][j] *= s;
        }
    } else if (og == 0) {
        #pragma unroll
        for (int i = 0; i < 4; ++i)
            qnorm[b * HW + n0 + ng * 4 + i] = sqrtf(tot[i]);
    }

    {
        float* __restrict__ T = z ? Pt : Qt;
        #pragma unroll
        for (int i = 0; i < 4; ++i) {
            size_t tb = ((size_t)b * HW + n0 + ng * 4 + i) * 128 + og * 8;
            *(float4*)&T[tb]     = make_float4(acc[i][0], acc[i][1], acc[i][2], acc[i][3]);
            *(float4*)&T[tb + 4] = make_float4(acc[i][4], acc[i][5], acc[i][6], acc[i][7]);
        }
    }
    {
        ushort* __restrict__ PK = z ? Ppk : Qpk;
        const int ks = og >> 1;
        #pragma unroll
        for (int i = 0; i < 4; ++i) {
            const int na  = n0 + ng * 4 + i;
            const int t32 = na >> 5;
            const int lt  = (na & 31) + 32 * (og & 1);
            ushort u[8];
            #pragma unroll
            for (int k = 0; k < 8; ++k) u[k] = f2bf_rne(acc[i][k]);
            size_t pk = ((((size_t)b * 128 + t32) * 8 + ks) * 64 + lt) * 8;
            uint4 w;
            w.x = (unsigned)u[0] | ((unsigned)u[1] << 16);
            w.y = (unsigned)u[2] | ((unsigned)u[3] << 16);
            w.z = (unsigned)u[4] | ((unsigned)u[5] << 16);
            w.w = (unsigned)u[6] | ((unsigned)u[7] << 16);
            *(uint4*)&PK[pk] = w;
        }
    }
}

// ---------------------------------------------------------------------------
// SINGLE sim pass, v3: staged-B + register-Q + 4x grid.
// R4 forensics: LDS-free variant was latency-bound (Mfma 13%, VALU 28%,
// HBM 24%, Occ 38% - nothing saturated): 8 L2-latency loads feed a serially
// dependent 8-MFMA chain with too few waves to hide it.  R1's LDS-staged
// variant ran <41us at only 8 waves/CU.  Combine: B cooperatively staged in
// 32 KB LDS (ONE barrier per block), Q in registers, grid (32,4,32) = 4096
// blocks -> 4-5 blocks/CU = 16-20 waves/CU.  Per-(n,m) MFMA chain order
// unchanged -> bitwise-same codes; Vmax = 32 exact slices merged by fmaxf.
// ---------------------------------------------------------------------------
__global__ __launch_bounds__(256, 4) void sim_sketch_kernel(
    const ushort* __restrict__ Qpk, const ushort* __restrict__ Ppk,
    const float* __restrict__ qnorm,
    float* __restrict__ Vmax, unsigned char* __restrict__ SK,
    unsigned char* __restrict__ CM)
{
    __shared__ ushort Bs[16384];   // 32 KB: 4 t32-rows of Ppk

    const int tid  = threadIdx.x;
    const int lane = tid & 63;
    const int w    = tid >> 6;
    const int nb   = blockIdx.x;
    const int b    = blockIdx.y;
    const int ms   = blockIdx.z;               // 0..31, 128 m's each
    const int hi   = lane >> 5;

    // stage B: t32-rows ms*4..+4 (32 KB), cooperative, coalesced
    {
        const uint4* src = (const uint4*)(Ppk + ((size_t)(b * 128 + ms * 4)) * 4096);
        uint4* dst = (uint4*)Bs;
        #pragma unroll
        for (int it = 0; it < 8; ++it) dst[it * 256 + tid] = src[it * 256 + tid];
    }

    // Q fragments: 8 x bf16x8 (32 VGPRs), loaded once, coalesced (L2-hit)
    const ushort* __restrict__ qbase =
        Qpk + ((size_t)(b * 128 + nb * 4)) * 4096 + (size_t)lane * 8;
    bf16x8 qf[8];
    #pragma unroll
    for (int ks = 0; ks < 8; ++ks)
        qf[ks] = *(const bf16x8*)(qbase + (w * 8 + ks) * 512);

    // per-n reciprocal scales (same expression as scan side)
    float rq[16];
    #pragma unroll
    for (int r = 0; r < 16; ++r) {
        int nl_ = (r & 3) + 8 * (r >> 2) + 4 * hi;
        rq[r] = 256.0f / qnorm[b * HW + nb * 128 + w * 32 + nl_];
    }

    const size_t g16f = (size_t)b * 256 + (size_t)(nb * 4 + w) * 2 + hi;
    const int mb0 = ms * 128 + (lane & 31);

    float bestv[16];
    #pragma unroll
    for (int r = 0; r < 16; ++r) bestv[r] = -1e30f;

    __syncthreads();   // Bs ready

    #pragma unroll 2
    for (int mtl = 0; mtl < 4; ++mtl) {
        f32x16 acc;
        #pragma unroll
        for (int r = 0; r < 16; ++r) acc[r] = 0.f;
        #pragma unroll
        for (int ks = 0; ks < 8; ++ks) {
            bf16x8 bb = *(const bf16x8*)&Bs[((mtl * 8 + ks) * 64 + lane) * 8];
            acc = __builtin_amdgcn_mfma_f32_32x32x16_bf16(qf[ks], bb, acc, 0, 0, 0);
        }
        #pragma unroll
        for (int r = 0; r < 16; ++r)
            bestv[r] = fmaxf(bestv[r], acc[r]);

        // scaled values; codes derive from exactly these products
        float x[16];
        #pragma unroll
        for (int r = 0; r < 16; ++r) x[r] = acc[r] * rq[r];

        // group colmax bound: cm8 >= rne(x[r]) for all r.
        float c0 = fmaxf(fmaxf(fmaxf(x[0], x[1]), fmaxf(x[2], x[3])),
                         fmaxf(fmaxf(x[4], x[5]), fmaxf(x[6], x[7])));
        float c1 = fmaxf(fmaxf(fmaxf(x[8], x[9]), fmaxf(x[10], x[11])),
                         fmaxf(fmaxf(x[12], x[13]), fmaxf(x[14], x[15])));
        int cmi = (int)(fmaxf(c0, c1) + 0.5f) + 1;
        cmi = cmi < 0 ? 0 : (cmi > 255 ? 255 : cmi);

        unsigned dw[4] = {0u, 0u, 0u, 0u};
        #pragma unroll
        for (int r = 0; r < 16; ++r) {
#if __has_builtin(__builtin_amdgcn_cvt_pk_u8_f32)
            dw[r >> 2] = (unsigned)__builtin_amdgcn_cvt_pk_u8_f32(
                x[r], (unsigned)(r & 3), (int)dw[r >> 2]);
#else
            int vi = (int)rintf(x[r]);
            vi = vi < 0 ? 0 : (vi > 255 ? 255 : vi);
            dw[r >> 2] |= (unsigned)vi << (8 * (r & 3));
#endif
        }
        const int m = mb0 + mtl * 32;
        uint4 pk;
        pk.x = dw[0]; pk.y = dw[1]; pk.z = dw[2]; pk.w = dw[3];
        *(uint4*)(SK + ((g16f * 4096 + (size_t)m) << 4)) = pk;
        CM[g16f * 4096 + (size_t)m] = (unsigned char)cmi;
    }

    #pragma unroll
    for (int r = 0; r < 16; ++r) {
        float v = bestv[r];
        #pragma unroll
        for (int d = 1; d < 32; d <<= 1)
            v = fmaxf(v, __shfl_xor(v, d, 64));
        if ((lane & 31) == 0) {
            int nl_ = (r & 3) + 8 * (r >> 2) + 4 * hi;
            int na = nb * 128 + w * 32 + nl_;
            Vmax[((size_t)b * HW + na) * 32 + ms] = v;
        }
    }
}

// ---------------------------------------------------------------------------
// fused init + threshold + scan + exact fp32 rescore.  One block per (b,g16):
// - inits the 16 best[n] slots it exclusively owns
// - computes t8 thresholds from Vmax (32 slices)/qnorm in-block
// - group-gates on the CM byte (skip 16B sketch word when cm8 < min t8)
// - byte-compares surviving words, exact fp32 dot per hit.
// ---------------------------------------------------------------------------
__device__ __noinline__ void dot_one_slow(
    const float* Qsrow, const float* __restrict__ Pt,
    int b, int m, int n, unsigned long long* __restrict__ best)
{
    const float4* __restrict__ pr = (const float4*)&Pt[((size_t)b * HW + m) * 128];
    float acc = 0.f;
    #pragma unroll
    for (int k = 0; k < 32; ++k) {
        float4 pv = pr[k];
        float4 qv = *(const float4*)&Qsrow[k * 4];
        acc += qv.x * pv.x + qv.y * pv.y + qv.z * pv.z + qv.w * pv.w;
    }
    unsigned u = __float_as_uint(acc);
    unsigned kk = (u & 0x80000000u) ? ~u : (u | 0x80000000u);
    unsigned long long key = ((unsigned long long)kk << 32) | (unsigned)(4095 - m);
    atomicMax(&best[(size_t)b * HW + n], key);
}

__global__ __launch_bounds__(256) void scan_rescore_kernel(
    const unsigned char* __restrict__ SK, const unsigned char* __restrict__ CM,
    const float* __restrict__ Vmax, const float* __restrict__ qnorm,
    const float* __restrict__ Qt, const float* __restrict__ Pt,
    unsigned long long* __restrict__ best)
{
    __shared__ float Qs[16][132];
    __shared__ int nlist[16];
    __shared__ int t8s[16];
    __shared__ ushort hl[LCAP];
    __shared__ unsigned lcnt;

    const int fg  = blockIdx.x;               // b*256 + g16
    const int tid = threadIdx.x;
    const int b = fg >> 8, g = fg & 255, t = g >> 1, gs = g & 1;

    if (tid == 0) lcnt = 0u;
    if (tid < 16) {
        int n = t * 32 + (tid & 3) + 8 * (tid >> 2) + 4 * gs;
        nlist[tid] = n;
        best[(size_t)b * HW + n] = 0ull;      // folded init: block-exclusive n
        float gmax = -1e30f;
        const float4* vs = (const float4*)&Vmax[((size_t)b * HW + n) * 32];
        #pragma unroll
        for (int s = 0; s < 8; ++s) {
            float4 v = vs[s];
            gmax = fmaxf(gmax, fmaxf(fmaxf(v.x, v.y), fmaxf(v.z, v.w)));
        }
        float qn  = qnorm[b * HW + n];
        float thr = gmax - (0.016f * qn + 1e-6f);
        int tt = (int)floorf(thr * (256.0f / qn)) - 1;
        t8s[tid] = tt < 0 ? 0 : (tt > 255 ? 255 : tt);
    }
    __syncthreads();

    #pragma unroll
    for (int it = 0; it < 2; ++it) {
        int idx = it * 256 + tid;
        int row = idx >> 5, c4 = (idx & 31) * 4;
        *(float4*)&Qs[row][c4] =
            *(const float4*)&Qt[((size_t)b * HW + nlist[row]) * 128 + c4];
    }

    int myt[16];
    #pragma unroll
    for (int j = 0; j < 16; ++j) myt[j] = t8s[j];
    int gmin = myt[0];
    #pragma unroll
    for (int j = 1; j < 16; ++j) gmin = min(gmin, myt[j]);
    __syncthreads();   // Qs staged (inline-overflow dots read it)

    const unsigned char* __restrict__ cmrow = CM + ((size_t)fg << 12);
    const unsigned char* __restrict__ skrow = SK + ((size_t)fg << 16);

    #pragma unroll
    for (int it = 0; it < 4; ++it) {
        int m0 = (it * 256 + tid) * 4;
        unsigned cm4 = *(const unsigned*)(cmrow + m0);
        #pragma unroll
        for (int k = 0; k < 4; ++k) {
            int cmv = (int)((cm4 >> (8 * k)) & 255u);
            if (cmv >= gmin) {
                int m = m0 + k;
                uint4 v = *(const uint4*)(skrow + ((size_t)m << 4));
                unsigned wv[4] = {v.x, v.y, v.z, v.w};
                #pragma unroll
                for (int d = 0; d < 4; ++d) {
                    #pragma unroll
                    for (int kk = 0; kk < 4; ++kk) {
                        int bv = (int)((wv[d] >> (8 * kk)) & 255u);
                        int j = d * 4 + kk;
                        if (bv >= myt[j]) {
                            unsigned pos = atomicAdd(&lcnt, 1u);
                            if (pos < LCAP) {
                                hl[pos] = (ushort)((j << 12) | m);
                            } else {   // overflow: inline (rare/never)
                                dot_one_slow(&Qs[j][0], Pt, b, m, nlist[j], best);
                            }
                        }
                    }
                }
            }
        }
    }

    __syncthreads();
    unsigned cnt = lcnt < LCAP ? lcnt : LCAP;
    for (unsigned p = tid; p < cnt; p += 256) {
        int e = hl[p];
        int j = e >> 12, m = e & 4095;
        const float4* __restrict__ pr = (const float4*)&Pt[((size_t)b * HW + m) * 128];
        float acc = 0.f;
        #pragma unroll
        for (int k = 0; k < 32; ++k) {
            float4 pv = pr[k];
            float4 qv = *(const float4*)&Qs[j][k * 4];
            acc += qv.x * pv.x + qv.y * pv.y + qv.z * pv.z + qv.w * pv.w;
        }
        unsigned u = __float_as_uint(acc);
        unsigned kk = (u & 0x80000000u) ? ~u : (u | 0x80000000u);
        unsigned long long key = ((unsigned long long)kk << 32) | (unsigned)(4095 - m);
        atomicMax(&best[(size_t)b * HW + nlist[j]], key);
    }
}

// ---------------------------------------------------------------------------
// gather: out[b][c][n] = Fp[b][c][m(n)]; stage each 16 KB Fp row in LDS.
// ---------------------------------------------------------------------------
__global__ __launch_bounds__(256) void gather_kernel(
    const float* __restrict__ Fp, const unsigned long long* __restrict__ best,
    float* __restrict__ out)
{
    __shared__ float row[4096];
    const int blk = blockIdx.x;      // 1024 = 4b x 256c
    const int c = blk & 255;
    const int b = blk >> 8;
    const int tid = threadIdx.x;

    const float* __restrict__ src = Fp + ((size_t)b * 256 + c) * HW;
    #pragma unroll
    for (int it = 0; it < 4; ++it) {
        int f = it * 256 + tid;
        *(float4*)&row[f * 4] = *(const float4*)&src[f * 4];
    }
    __syncthreads();

    float* __restrict__ dst = out + ((size_t)b * 256 + c) * HW;
    #pragma unroll
    for (int it = 0; it < 16; ++it) {
        int n = it * 256 + tid;
        int m = 4095 - (int)(best[(size_t)b * HW + n] & 0xFFFull);
        dst[n] = row[m];
    }
}

extern "C" void kernel_launch(void* const* d_in, const int* in_sizes, int n_in,
                              void* d_out, int out_size, void* d_ws, size_t ws_size,
                              hipStream_t stream) {
    const float* Fq   = (const float*)d_in[0];
    const float* Fp   = (const float*)d_in[1];
    const float* Wm   = (const float*)d_in[2];
    const float* bias = (const float*)d_in[3];
    float* out = (float*)d_out;

    char* base = (char*)d_ws;
    float*  Qt    = (float*)(base);                               // 8 MB
    float*  Pt    = (float*)(base + (8u << 20));                  // 8 MB
    ushort* Qpk   = (ushort*)(base + (16u << 20));                // 4 MB
    ushort* Ppk   = (ushort*)(base + (20u << 20));                // 4 MB
    unsigned char* SK = (unsigned char*)(base + (24u << 20));     // 64 MB
    unsigned char* CM = (unsigned char*)(base + (88u << 20));     // 4 MB
    char* x = base + (92u << 20);
    float*  qnorm = (float*)x;              x += 65536;           // 64 KB
    float*  Vmax  = (float*)x;              x += 2097152;         // 2 MB (32 slices)
    unsigned long long* best = (unsigned long long*)x; x += 131072; // 128 KB
    float*  Wtg   = (float*)x;                                    // 128 KB

    transpose_w_kernel<<<128, 256, 0, stream>>>(Wm, Wtg);
    proj_kernel<<<dim3(64, 4, 2), 256, 0, stream>>>(Fq, Fp, Wtg, bias,
                                                    Qt, Pt, Qpk, Ppk, qnorm);
    sim_sketch_kernel<<<dim3(32, 4, 32), 256, 0, stream>>>(Qpk, Ppk, qnorm,
                                                           Vmax, SK, CM);
    scan_rescore_kernel<<<1024, 256, 0, stream>>>(SK, CM, Vmax, qnorm,
                                                  Qt, Pt, best);
    gather_kernel<<<1024, 256, 0, stream>>>(Fp, best, out);
}